// Round 12
// baseline (693.642 us; speedup 1.0000x reference)
//
#include <hip/hip_runtime.h>
#include <math.h>

// Problem constants: B=4, N=32768, D=256, H=8, S=64, DH=32
#define TS_N 32768
#define TS_M 131072   // B*N

typedef short bf16x8 __attribute__((ext_vector_type(8)));
typedef float f32x4  __attribute__((ext_vector_type(4)));
typedef unsigned short us4 __attribute__((ext_vector_type(4)));
typedef unsigned short us8 __attribute__((ext_vector_type(8)));

static __device__ __forceinline__ unsigned short f2bf(float f) {
    unsigned u = __float_as_uint(f);
    u = u + 0x7FFF + ((u >> 16) & 1);   // RNE
    return (unsigned short)(u >> 16);
}
static __device__ __forceinline__ float bf2f(unsigned short b) {
    return __uint_as_float(((unsigned)b) << 16);
}

// async global->LDS, 16B per lane; LDS dest = wave-uniform base + lane*16
#define GL16(gp, lp) __builtin_amdgcn_global_load_lds( \
    (const __attribute__((address_space(1))) unsigned int*)(gp), \
    (__attribute__((address_space(3))) unsigned int*)(lp), 16, 0, 0)

// ---------------------------------------------------------------------------
// K0w: convert + transpose Wfx, Wx -> Wt[w][n][k] bf16 hi/lo
// ---------------------------------------------------------------------------
__global__ __launch_bounds__(256) void k0_wt(
    const float* __restrict__ Wfx, const float* __restrict__ Wx,
    unsigned short* __restrict__ Wth, unsigned short* __restrict__ Wtl)
{
    const int n = blockIdx.x;       // 0..255 (output col of W = row of Wt)
    const int wsel = blockIdx.y;    // 0..1
    const int k = threadIdx.x;      // 0..255
    const float v = (wsel ? Wx : Wfx)[k * 256 + n];
    const unsigned short hh = f2bf(v);
    const int idx = (wsel * 256 + n) * 256 + k;
    Wth[idx] = hh;
    Wtl[idx] = f2bf(v - bf2f(hh));
}

// ---------------------------------------------------------------------------
// K1: FX/XM GEMM, reads x (f32) directly (inline hi/lo split in A-staging).
// 2-PHASE DOUBLE-BUFFER (T3 minimum recipe + T14 write-late A-publish):
// per step: issue next tile's loads into buf^1 (B gload_lds; A global->reg),
// ds_read frags + 48 MFMAs on buf[cur], convert+ds_write A regs to buf^1,
// ONE barrier (drains vmcnt -> buf^1 valid). Load latency hides under MFMA.
// 4096 blocks, XCD-swizzled. BM=128,BN=128,BK=32, 4 waves, split-bf16.
// LDS 64 KB -> 2 blocks/CU.
// ---------------------------------------------------------------------------
__global__ __launch_bounds__(256) void k1_gemm(
    const float* __restrict__ x,
    const unsigned short* __restrict__ Wth, const unsigned short* __restrict__ Wtl,
    const float* __restrict__ bfx, const float* __restrict__ bx,
    float* __restrict__ FX, float* __restrict__ XM)
{
    __shared__ unsigned short AldsH[2][4096];
    __shared__ unsigned short AldsL[2][4096];
    __shared__ unsigned short BldsH[2][4096];
    __shared__ unsigned short BldsL[2][4096];

    const int L = blockIdx.x;
    const int xcd = L & 7, ii = L >> 3;
    const int rb = xcd * 128 + (ii >> 2), nsel = ii & 3;
    const int row0 = rb * 128;
    const int n0 = (nsel & 1) * 128;
    const unsigned short* Bth = Wth + (nsel >> 1) * 65536 + n0 * 256;
    const unsigned short* Btl = Wtl + (nsel >> 1) * 65536 + n0 * 256;
    const float* bias = (nsel >> 1) ? bx : bfx;
    float* OUT = (nsel >> 1) ? XM : FX;

    const int t = threadIdx.x;
    const int w = t >> 6, l = t & 63;
    const int wm = w >> 1, wn = w & 1;
    const int lr = l & 15, lk = l >> 4;

    f32x4 acc[4][4];
#pragma unroll
    for (int i = 0; i < 4; ++i)
#pragma unroll
        for (int j = 0; j < 4; ++j) {
            acc[i][j][0] = 0.f; acc[i][j][1] = 0.f;
            acc[i][j][2] = 0.f; acc[i][j][3] = 0.f;
        }

    // prologue: stage tile 0 into buf 0
#pragma unroll
    for (int g2i = 0; g2i < 2; ++g2i) {
        const int g2 = w + g2i * 4;
        const size_t br = (size_t)(g2 * 16 + lr) * 256 + lk * 8;
        const int lb = g2 * 512;
        GL16(Bth + br, &BldsH[0][lb]);
        GL16(Btl + br, &BldsL[0][lb]);
    }
#pragma unroll
    for (int g2i = 0; g2i < 2; ++g2i) {
        const int g2 = w + g2i * 4;
        const float* ap = &x[(size_t)(row0 + g2 * 16 + lr) * 256 + lk * 8];
        float4 a0 = *(const float4*)ap;
        float4 a1 = *(const float4*)(ap + 4);
        float cc[8] = {a0.x, a0.y, a0.z, a0.w, a1.x, a1.y, a1.z, a1.w};
        us8 vh, vl;
#pragma unroll
        for (int j = 0; j < 8; ++j) {
            const unsigned short hb = f2bf(cc[j]);
            vh[j] = hb;
            vl[j] = f2bf(cc[j] - bf2f(hb));
        }
        *(us8*)&AldsH[0][(g2 * 64 + l) * 8] = vh;
        *(us8*)&AldsL[0][(g2 * 64 + l) * 8] = vl;
    }
    __syncthreads();   // tile 0 valid

    int cur = 0;
    for (int step = 0; step < 8; ++step) {
        float4 pa0[2], pa1[2];
        if (step < 7) {
            const int kk = (step + 1) * 32;
            // B: async gload_lds into buf^1 (in flight across the MFMAs)
#pragma unroll
            for (int g2i = 0; g2i < 2; ++g2i) {
                const int g2 = w + g2i * 4;
                const size_t br = (size_t)(g2 * 16 + lr) * 256 + kk + lk * 8;
                const int lb = g2 * 512;
                GL16(Bth + br, &BldsH[cur ^ 1][lb]);
                GL16(Btl + br, &BldsL[cur ^ 1][lb]);
            }
            // A: issue global f32 loads early (consumed after MFMAs)
#pragma unroll
            for (int g2i = 0; g2i < 2; ++g2i) {
                const int g2 = w + g2i * 4;
                const float* ap = &x[(size_t)(row0 + g2 * 16 + lr) * 256 + kk + lk * 8];
                pa0[g2i] = *(const float4*)ap;
                pa1[g2i] = *(const float4*)(ap + 4);
            }
        }

        bf16x8 ah[4], al[4], bh[4], bl[4];
#pragma unroll
        for (int g = 0; g < 4; ++g) {
            const int ac = (((wm * 4 + g) * 4 + lk) * 16 + lr) * 8;
            ah[g] = *(const bf16x8*)&AldsH[cur][ac];
            al[g] = *(const bf16x8*)&AldsL[cur][ac];
            const int bc = (((wn * 4 + g) * 4 + lk) * 16 + lr) * 8;
            bh[g] = *(const bf16x8*)&BldsH[cur][bc];
            bl[g] = *(const bf16x8*)&BldsL[cur][bc];
        }
#pragma unroll
        for (int m = 0; m < 4; ++m)
#pragma unroll
            for (int n = 0; n < 4; ++n) {
                acc[m][n] = __builtin_amdgcn_mfma_f32_16x16x32_bf16(ah[m], bh[n], acc[m][n], 0, 0, 0);
                acc[m][n] = __builtin_amdgcn_mfma_f32_16x16x32_bf16(ah[m], bl[n], acc[m][n], 0, 0, 0);
                acc[m][n] = __builtin_amdgcn_mfma_f32_16x16x32_bf16(al[m], bh[n], acc[m][n], 0, 0, 0);
            }

        if (step < 7) {
            // write-late: convert A regs (loads had the MFMA burst to land)
#pragma unroll
            for (int g2i = 0; g2i < 2; ++g2i) {
                const int g2 = w + g2i * 4;
                float cc[8] = {pa0[g2i].x, pa0[g2i].y, pa0[g2i].z, pa0[g2i].w,
                               pa1[g2i].x, pa1[g2i].y, pa1[g2i].z, pa1[g2i].w};
                us8 vh, vl;
#pragma unroll
                for (int j = 0; j < 8; ++j) {
                    const unsigned short hb = f2bf(cc[j]);
                    vh[j] = hb;
                    vl[j] = f2bf(cc[j] - bf2f(hb));
                }
                *(us8*)&AldsH[cur ^ 1][(g2 * 64 + l) * 8] = vh;
                *(us8*)&AldsL[cur ^ 1][(g2 * 64 + l) * 8] = vl;
            }
        }
        __syncthreads();   // drains vmcnt+lgkm: buf^1 valid; buf[cur] free
        cur ^= 1;
    }

    float bv[4];
#pragma unroll
    for (int n = 0; n < 4; ++n) bv[n] = bias[n0 + wn * 64 + n * 16 + lr];
#pragma unroll
    for (int m = 0; m < 4; ++m)
#pragma unroll
        for (int n = 0; n < 4; ++n) {
            const int col = n0 + wn * 64 + n * 16 + lr;
#pragma unroll
            for (int r = 0; r < 4; ++r) {
                const int row = row0 + wm * 64 + m * 16 + lk * 4 + r;
                OUT[(size_t)row * 256 + col] = acc[m][n][r] + bv[n];
            }
        }
}

// ---------------------------------------------------------------------------
// K1b: logits = XM_head @ W_slice + b_slice, /temp[h], softmax over S=64.
// Writes SW as bf16 hi/lo pairs (SWh, SWl) [M][512].
// ---------------------------------------------------------------------------
__global__ __launch_bounds__(256) void k1b_slice_softmax(
    const float* __restrict__ XM, const float* __restrict__ Wsl,
    const float* __restrict__ bsl, const float* __restrict__ temp,
    unsigned short* __restrict__ SWh, unsigned short* __restrict__ SWl)
{
    __shared__ float XMs[32][68];  // [c][m]
    __shared__ float Ws[32][68];   // [c][s]
    __shared__ float Ls[64][68];   // logits tile [row][s]
    const int t  = threadIdx.x;
    const int r0 = blockIdx.x * 64;
    const int h  = blockIdx.y;

    {
        const int m = t >> 2, cq = (t & 3) * 8;
        float4 v0 = *(const float4*)&XM[(size_t)(r0 + m) * 256 + h * 32 + cq];
        float4 v1 = *(const float4*)&XM[(size_t)(r0 + m) * 256 + h * 32 + cq + 4];
        XMs[cq + 0][m] = v0.x; XMs[cq + 1][m] = v0.y; XMs[cq + 2][m] = v0.z; XMs[cq + 3][m] = v0.w;
        XMs[cq + 4][m] = v1.x; XMs[cq + 5][m] = v1.y; XMs[cq + 6][m] = v1.z; XMs[cq + 7][m] = v1.w;
        const int wk = t >> 3, wn = (t & 7) * 8;
        float4 u0 = *(const float4*)&Wsl[wk * 64 + wn];
        float4 u1 = *(const float4*)&Wsl[wk * 64 + wn + 4];
        *(float4*)&Ws[wk][wn]     = u0;
        *(float4*)&Ws[wk][wn + 4] = u1;
    }
    __syncthreads();

    const int tx = t & 15, ty = t >> 4;
    float acc[4][4];
#pragma unroll
    for (int i = 0; i < 4; ++i)
#pragma unroll
        for (int j = 0; j < 4; ++j) acc[i][j] = 0.f;
#pragma unroll
    for (int c = 0; c < 32; ++c) {
        float4 av = *(const float4*)&XMs[c][ty * 4];
        float4 bv = *(const float4*)&Ws[c][tx * 4];
        float a_[4] = {av.x, av.y, av.z, av.w};
        float b_[4] = {bv.x, bv.y, bv.z, bv.w};
#pragma unroll
        for (int i = 0; i < 4; ++i)
#pragma unroll
            for (int j = 0; j < 4; ++j)
                acc[i][j] = fmaf(a_[i], b_[j], acc[i][j]);
    }
    const float invt = 1.0f / temp[h];
#pragma unroll
    for (int i = 0; i < 4; ++i)
#pragma unroll
        for (int j = 0; j < 4; ++j)
            Ls[ty * 4 + i][tx * 4 + j] = (acc[i][j] + bsl[tx * 4 + j]) * invt;
    __syncthreads();

    const int row = t >> 2, j4 = t & 3;
    float v[16];
    float mx = -1e30f;
#pragma unroll
    for (int i = 0; i < 16; ++i) { v[i] = Ls[row][j4 * 16 + i]; mx = fmaxf(mx, v[i]); }
    mx = fmaxf(mx, __shfl_xor(mx, 1));
    mx = fmaxf(mx, __shfl_xor(mx, 2));
    float sum = 0.f;
#pragma unroll
    for (int i = 0; i < 16; ++i) { v[i] = expf(v[i] - mx); sum += v[i]; }
    sum += __shfl_xor(sum, 1);
    sum += __shfl_xor(sum, 2);
    const float inv = 1.0f / sum;
#pragma unroll
    for (int q = 0; q < 4; ++q) {
        us4 oh, ol;
#pragma unroll
        for (int j = 0; j < 4; ++j) {
            const float o = v[q * 4 + j] * inv;
            const unsigned short hh = f2bf(o);
            oh[j] = hh;
            ol[j] = f2bf(o - bf2f(hh));
        }
        const size_t idx = (size_t)(r0 + row) * 512 + h * 64 + j4 * 16 + q * 4;
        *(us4*)&SWh[idx] = oh;
        *(us4*)&SWl[idx] = ol;
    }
}

// ---------------------------------------------------------------------------
// K4: out = SW[131072x512] @ Gt_b^T + bout. 2048 blocks, XCD-swizzled pairs.
// 2-phase double-buffered gload_lds staging, split-bf16 body, K=512.
// ---------------------------------------------------------------------------
__global__ __launch_bounds__(256) void k4_gemm(
    const unsigned short* __restrict__ SWh, const unsigned short* __restrict__ SWl,
    const unsigned short* __restrict__ Gth, const unsigned short* __restrict__ Gtl,
    const float* __restrict__ bout, float* __restrict__ out)
{
    __shared__ unsigned short Alds[2][2][4096];   // [buf][hi/lo]
    __shared__ unsigned short Blds[2][2][4096];
    const int L = blockIdx.x;
    const int xcd = L & 7, ii = L >> 3;
    const int rb = xcd * 128 + (ii >> 1), nsel = ii & 1;
    const int row0 = rb * 128;
    const int n0 = nsel * 128;
    const int b = row0 >> 15;
    const unsigned short* Bth = Gth + ((size_t)b * 256 + n0) * 512;
    const unsigned short* Btl = Gtl + ((size_t)b * 256 + n0) * 512;

    const int t = threadIdx.x;
    const int w = t >> 6, l = t & 63;
    const int wm = w >> 1, wn = w & 1;
    const int lr = l & 15, lk = l >> 4;

    f32x4 acc[4][4];
#pragma unroll
    for (int i = 0; i < 4; ++i)
#pragma unroll
        for (int j = 0; j < 4; ++j) {
            acc[i][j][0] = 0.f; acc[i][j][1] = 0.f;
            acc[i][j][2] = 0.f; acc[i][j][3] = 0.f;
        }

    // prologue: stage tile 0 into buf 0
#pragma unroll
    for (int g2i = 0; g2i < 2; ++g2i) {
        const int g2 = w + g2i * 4;
        const size_t ar = (size_t)(row0 + g2 * 16 + lr) * 512 + lk * 8;
        const size_t br = (size_t)(g2 * 16 + lr) * 512 + lk * 8;
        const int lb = g2 * 512;
        GL16(SWh + ar, &Alds[0][0][lb]);
        GL16(SWl + ar, &Alds[0][1][lb]);
        GL16(Bth + br, &Blds[0][0][lb]);
        GL16(Btl + br, &Blds[0][1][lb]);
    }
    __syncthreads();

    int cur = 0;
    for (int step = 0; step < 16; ++step) {
        if (step < 15) {
            const int kk = (step + 1) * 32;
#pragma unroll
            for (int g2i = 0; g2i < 2; ++g2i) {
                const int g2 = w + g2i * 4;
                const size_t ar = (size_t)(row0 + g2 * 16 + lr) * 512 + kk + lk * 8;
                const size_t br = (size_t)(g2 * 16 + lr) * 512 + kk + lk * 8;
                const int lb = g2 * 512;
                GL16(SWh + ar, &Alds[cur ^ 1][0][lb]);
                GL16(SWl + ar, &Alds[cur ^ 1][1][lb]);
                GL16(Bth + br, &Blds[cur ^ 1][0][lb]);
                GL16(Btl + br, &Blds[cur ^ 1][1][lb]);
            }
        }

        bf16x8 ah[4], al[4], bh[4], bl[4];
#pragma unroll
        for (int g = 0; g < 4; ++g) {
            const int ac = (((wm * 4 + g) * 4 + lk) * 16 + lr) * 8;
            ah[g] = *(const bf16x8*)&Alds[cur][0][ac];
            al[g] = *(const bf16x8*)&Alds[cur][1][ac];
            const int bc = (((wn * 4 + g) * 4 + lk) * 16 + lr) * 8;
            bh[g] = *(const bf16x8*)&Blds[cur][0][bc];
            bl[g] = *(const bf16x8*)&Blds[cur][1][bc];
        }
#pragma unroll
        for (int m = 0; m < 4; ++m)
#pragma unroll
            for (int n = 0; n < 4; ++n) {
                acc[m][n] = __builtin_amdgcn_mfma_f32_16x16x32_bf16(ah[m], bh[n], acc[m][n], 0, 0, 0);
                acc[m][n] = __builtin_amdgcn_mfma_f32_16x16x32_bf16(ah[m], bl[n], acc[m][n], 0, 0, 0);
                acc[m][n] = __builtin_amdgcn_mfma_f32_16x16x32_bf16(al[m], bh[n], acc[m][n], 0, 0, 0);
            }
        __syncthreads();   // drains vmcnt: buf^1 valid; buf[cur] free
        cur ^= 1;
    }

    float bv[4];
#pragma unroll
    for (int n = 0; n < 4; ++n) bv[n] = bout[n0 + wn * 64 + n * 16 + lr];
#pragma unroll
    for (int m = 0; m < 4; ++m)
#pragma unroll
        for (int n = 0; n < 4; ++n) {
            const int col = n0 + wn * 64 + n * 16 + lr;
#pragma unroll
            for (int r = 0; r < 4; ++r) {
                const int row = row0 + wm * 64 + m * 16 + lk * 4 + r;
                out[(size_t)row * 256 + col] = acc[m][n][r] + bv[n];
            }
        }
}

// ---------------------------------------------------------------------------
// K2: partial pooling. Grid (64 chunks x 32 bh), 512 rows/chunk.
// 64-row slabs, reg-prefetch + double-buffered LDS, ONE barrier per slab.
// ---------------------------------------------------------------------------
__global__ __launch_bounds__(256) void k2_pool(
    const float* __restrict__ FX,
    const unsigned short* __restrict__ SWh, const unsigned short* __restrict__ SWl,
    float* __restrict__ PART, float* __restrict__ PARTN)
{
    __shared__ float SWs[2][64][68];
    __shared__ float FXs[2][64][36];
    const int t = threadIdx.x;
    const int chunk = blockIdx.x;   // 0..63
    const int bh = blockIdx.y;      // 0..31
    const int b = bh >> 3, h = bh & 7;
    const int gbase = b * TS_N + chunk * 512;

    const int rs = t >> 2;          // staging row 0..63
    const int ch0 = t & 3;          // staging chunk: ch0 and ch0+4

    us8 swh[2], swl[2];
    float4 fxr[2];

    {
        const size_t swbase = (size_t)(gbase + rs) * 512 + h * 64;
        swh[0] = *(const us8*)&SWh[swbase + ch0 * 8];
        swh[1] = *(const us8*)&SWh[swbase + (ch0 + 4) * 8];
        swl[0] = *(const us8*)&SWl[swbase + ch0 * 8];
        swl[1] = *(const us8*)&SWl[swbase + (ch0 + 4) * 8];
        const size_t fxbase = (size_t)(gbase + rs) * 256 + h * 32;
        fxr[0] = *(const float4*)&FX[fxbase + ch0 * 4];
        fxr[1] = *(const float4*)&FX[fxbase + (ch0 + 4) * 4];
    }

    const int c = t & 31, sb = (t >> 5) * 8;
    float acc[8];
#pragma unroll
    for (int j = 0; j < 8; ++j) acc[j] = 0.f;
    float accn = 0.f;
    int buf = 0;

    for (int s = 0; s < 8; ++s) {
#pragma unroll
        for (int q = 0; q < 2; ++q) {
            const int cq = (ch0 + q * 4) * 8;
#pragma unroll
            for (int j = 0; j < 8; ++j)
                SWs[buf][rs][cq + j] = bf2f(swh[q][j]) + bf2f(swl[q][j]);
            *(float4*)&FXs[buf][rs][(ch0 + q * 4) * 4] = fxr[q];
        }
        __syncthreads();
        if (s < 7) {
            const int g2 = gbase + (s + 1) * 64 + rs;
            const size_t swbase = (size_t)g2 * 512 + h * 64;
            swh[0] = *(const us8*)&SWh[swbase + ch0 * 8];
            swh[1] = *(const us8*)&SWh[swbase + (ch0 + 4) * 8];
            swl[0] = *(const us8*)&SWl[swbase + ch0 * 8];
            swl[1] = *(const us8*)&SWl[swbase + (ch0 + 4) * 8];
            const size_t fxbase = (size_t)g2 * 256 + h * 32;
            fxr[0] = *(const float4*)&FX[fxbase + ch0 * 4];
            fxr[1] = *(const float4*)&FX[fxbase + (ch0 + 4) * 4];
        }
#pragma unroll 8
        for (int rr = 0; rr < 64; ++rr) {
            const float f = FXs[buf][rr][c];
            float4 s0 = *(const float4*)&SWs[buf][rr][sb];
            float4 s1 = *(const float4*)&SWs[buf][rr][sb + 4];
            acc[0] = fmaf(f, s0.x, acc[0]); acc[1] = fmaf(f, s0.y, acc[1]);
            acc[2] = fmaf(f, s0.z, acc[2]); acc[3] = fmaf(f, s0.w, acc[3]);
            acc[4] = fmaf(f, s1.x, acc[4]); acc[5] = fmaf(f, s1.y, acc[5]);
            acc[6] = fmaf(f, s1.z, acc[6]); acc[7] = fmaf(f, s1.w, acc[7]);
        }
        if (t < 64) {
#pragma unroll 8
            for (int rr = 0; rr < 64; ++rr) accn += SWs[buf][rr][t];
        }
        buf ^= 1;
    }

    const int pbase = (bh * 64 + chunk) * 2048;
#pragma unroll
    for (int j = 0; j < 8; ++j) PART[pbase + (sb + j) * 32 + c] = acc[j];
    if (t < 64) PARTN[(bh * 64 + chunk) * 64 + t] = accn;
}

// ---------------------------------------------------------------------------
// K2b: deterministic reduce of 64 chunk partials. Grid (8 groups x 32 bh).
// ---------------------------------------------------------------------------
__global__ __launch_bounds__(256) void k2b_reduce(
    const float* __restrict__ PART, const float* __restrict__ PARTN,
    float* __restrict__ ST, float* __restrict__ NORM)
{
    const int g = blockIdx.x, bh = blockIdx.y, t = threadIdx.x;
    const int e = g * 256 + t;
    float s = 0.f;
    for (int ch = 0; ch < 64; ++ch) s += PART[(size_t)(bh * 64 + ch) * 2048 + e];
    ST[bh * 2048 + e] = s;
    if (g == 0 && t < 64) {
        float sn = 0.f;
        for (int ch = 0; ch < 64; ++ch) sn += PARTN[(bh * 64 + ch) * 64 + t];
        NORM[bh * 64 + t] = sn;
    }
}

// ---------------------------------------------------------------------------
// K3: tiny attention among 64 slice tokens per (b,h). 1 wave per block.
// ---------------------------------------------------------------------------
__global__ __launch_bounds__(64) void k3_attn(
    const float* __restrict__ ST, const float* __restrict__ NORM,
    const float* __restrict__ Wqkv, float* __restrict__ OST)
{
    __shared__ float Wq[32 * 96];
    __shared__ float Kl[64][32];
    __shared__ float Vl[64][32];
    __shared__ float Dl[64][68];
    const int bh = blockIdx.x;
    const int s  = threadIdx.x;

    for (int i = 0; i < 48; ++i) Wq[i * 64 + s] = Wqkv[i * 64 + s];
    float st[32];
    const float nrm = NORM[bh * 64 + s] + 1e-5f;
#pragma unroll
    for (int c = 0; c < 32; ++c) st[c] = ST[bh * 2048 + s * 32 + c] / nrm;
    __syncthreads();

    float q[32];
#pragma unroll
    for (int o4 = 0; o4 < 8; ++o4) {
        float ax = 0.f, ay = 0.f, az = 0.f, aw = 0.f;
#pragma unroll
        for (int c = 0; c < 32; ++c) {
            float4 w = *(const float4*)&Wq[c * 96 + o4 * 4];
            ax = fmaf(st[c], w.x, ax); ay = fmaf(st[c], w.y, ay);
            az = fmaf(st[c], w.z, az); aw = fmaf(st[c], w.w, aw);
        }
        q[o4 * 4 + 0] = ax; q[o4 * 4 + 1] = ay; q[o4 * 4 + 2] = az; q[o4 * 4 + 3] = aw;
    }
#pragma unroll
    for (int o4 = 0; o4 < 8; ++o4) {
        float ax = 0.f, ay = 0.f, az = 0.f, aw = 0.f;
#pragma unroll
        for (int c = 0; c < 32; ++c) {
            float4 w = *(const float4*)&Wq[c * 96 + 32 + o4 * 4];
            ax = fmaf(st[c], w.x, ax); ay = fmaf(st[c], w.y, ay);
            az = fmaf(st[c], w.z, az); aw = fmaf(st[c], w.w, aw);
        }
        float4 kv; kv.x = ax; kv.y = ay; kv.z = az; kv.w = aw;
        *(float4*)&Kl[s][o4 * 4] = kv;
    }
#pragma unroll
    for (int o4 = 0; o4 < 8; ++o4) {
        float ax = 0.f, ay = 0.f, az = 0.f, aw = 0.f;
#pragma unroll
        for (int c = 0; c < 32; ++c) {
            float4 w = *(const float4*)&Wq[c * 96 + 64 + o4 * 4];
            ax = fmaf(st[c], w.x, ax); ay = fmaf(st[c], w.y, ay);
            az = fmaf(st[c], w.z, az); aw = fmaf(st[c], w.w, aw);
        }
        float4 vv; vv.x = ax; vv.y = ay; vv.z = az; vv.w = aw;
        *(float4*)&Vl[s][o4 * 4] = vv;
    }
    __syncthreads();

    const float scale = 0.17677669529663687f;  // 32^-0.5
    float mx = -1e30f;
    for (int t2 = 0; t2 < 64; ++t2) {
        float d = 0.f;
#pragma unroll
        for (int c4 = 0; c4 < 8; ++c4) {
            float4 kv = *(const float4*)&Kl[t2][c4 * 4];
            d = fmaf(q[c4 * 4 + 0], kv.x, d); d = fmaf(q[c4 * 4 + 1], kv.y, d);
            d = fmaf(q[c4 * 4 + 2], kv.z, d); d = fmaf(q[c4 * 4 + 3], kv.w, d);
        }
        d *= scale;
        Dl[s][t2] = d;
        mx = fmaxf(mx, d);
    }
    float sum = 0.f;
    for (int t2 = 0; t2 < 64; ++t2) { float e = expf(Dl[s][t2] - mx); Dl[s][t2] = e; sum += e; }
    const float inv = 1.0f / sum;
    float out[32];
#pragma unroll
    for (int c = 0; c < 32; ++c) out[c] = 0.f;
    for (int t2 = 0; t2 < 64; ++t2) {
        const float p = Dl[s][t2] * inv;
#pragma unroll
        for (int c4 = 0; c4 < 8; ++c4) {
            float4 vv = *(const float4*)&Vl[t2][c4 * 4];
            out[c4 * 4 + 0] = fmaf(p, vv.x, out[c4 * 4 + 0]);
            out[c4 * 4 + 1] = fmaf(p, vv.y, out[c4 * 4 + 1]);
            out[c4 * 4 + 2] = fmaf(p, vv.z, out[c4 * 4 + 2]);
            out[c4 * 4 + 3] = fmaf(p, vv.w, out[c4 * 4 + 3]);
        }
    }
#pragma unroll
    for (int c4 = 0; c4 < 8; ++c4) {
        float4 ov;
        ov.x = out[c4 * 4 + 0]; ov.y = out[c4 * 4 + 1];
        ov.z = out[c4 * 4 + 2]; ov.w = out[c4 * 4 + 3];
        *(float4*)&OST[bh * 2048 + s * 32 + c4 * 4] = ov;
    }
}

// ---------------------------------------------------------------------------
// K3b: G[b, h*64+s, :] = OST[bh,s,:] @ Wout[h*32:(h+1)*32, :], written
// TRANSPOSED as bf16 hi/lo: Gt[b][n=256][k=512].
// ---------------------------------------------------------------------------
__global__ __launch_bounds__(256) void k3b_precomb(
    const float* __restrict__ OST, const float* __restrict__ Wout,
    unsigned short* __restrict__ Gth, unsigned short* __restrict__ Gtl)
{
    __shared__ float OSTs[64][36];   // [s][c], padded
    __shared__ float Wc[32][256];    // [c][o]
    const int bh = blockIdx.x;
    const int b = bh >> 3, h = bh & 7;
    const int t = threadIdx.x;

#pragma unroll
    for (int j = 0; j < 2; ++j) {
        const int e = (j * 256 + t) * 4;       // 0..2044, step 4
        float4 v = *(const float4*)&OST[bh * 2048 + e];
        const int s = e >> 5, c = e & 31;
        OSTs[s][c + 0] = v.x; OSTs[s][c + 1] = v.y;
        OSTs[s][c + 2] = v.z; OSTs[s][c + 3] = v.w;
    }
#pragma unroll
    for (int j = 0; j < 8; ++j) {
        const int e = (j * 256 + t) * 4;       // 0..8188
        const int c = e >> 8, o = e & 255;
        *(float4*)&Wc[c][o] = *(const float4*)&Wout[(h * 32 + c) * 256 + o];
    }
    __syncthreads();

    float wcol[32];
#pragma unroll
    for (int c = 0; c < 32; ++c) wcol[c] = Wc[c][t];

    for (int s = 0; s < 64; ++s) {
        float a = 0.f;
#pragma unroll
        for (int c = 0; c < 32; ++c) a = fmaf(OSTs[s][c], wcol[c], a);
        const unsigned short gh = f2bf(a);
        const size_t idx = ((size_t)(b * 256 + t)) * 512 + h * 64 + s;
        Gth[idx] = gh;
        Gtl[idx] = f2bf(a - bf2f(gh));
    }
}

extern "C" void kernel_launch(void* const* d_in, const int* in_sizes, int n_in,
                              void* d_out, int out_size, void* d_ws, size_t ws_size,
                              hipStream_t stream) {
    (void)in_sizes; (void)n_in; (void)out_size; (void)ws_size;
    const float* x    = (const float*)d_in[0];
    const float* Wfx  = (const float*)d_in[1];
    const float* bfx  = (const float*)d_in[2];
    const float* Wx   = (const float*)d_in[3];
    const float* bx   = (const float*)d_in[4];
    const float* Wsl  = (const float*)d_in[5];
    const float* bsl  = (const float*)d_in[6];
    const float* temp = (const float*)d_in[7];
    const float* Wqkv = (const float*)d_in[8];
    const float* Wout = (const float*)d_in[9];
    const float* bout = (const float*)d_in[10];
    float* out = (float*)d_out;
    char* w = (char*)d_ws;

    // ws layout (bytes):
    // [0, 128M):       XM f32 (dead after k1b) -> reused for PART/PARTN by k2
    // [128M, 384M):    SWh | SWl
    // [384M+, ...):    ST/NORM/OST/Gt/Wt
    float* XM = (float*)w;
    unsigned short* SWh = (unsigned short*)(w + 134217728);
    unsigned short* SWl = SWh + 67108864;
    char* p = w + 134217728 + 268435456;
    float* ST    = (float*)p;            p += 262144;      // 65,536 f
    float* NORM  = (float*)p;            p += 8192;        // 2,048 f
    float* OST   = (float*)p;            p += 262144;      // 65,536 f
    unsigned short* Gth = (unsigned short*)p; p += 1048576; // 524,288 us
    unsigned short* Gtl = (unsigned short*)p; p += 1048576;
    unsigned short* Wth = (unsigned short*)p; p += 262144;  // 131,072 us
    unsigned short* Wtl = (unsigned short*)p; p += 262144;
    // PART/PARTN in the dead XM region
    float* PART  = XM;                   // 32*64*2048 = 4,194,304 f
    float* PARTN = XM + 4194304;         // 32*64*64  = 131,072 f
    float* FX = out;   // d_out doubles as FX scratch (read by k2, overwritten by k4)

    k0_wt<<<dim3(256, 2), 256, 0, stream>>>(Wfx, Wx, Wth, Wtl);
    k1_gemm<<<4096, 256, 0, stream>>>(x, Wth, Wtl, bfx, bx, FX, XM);
    k1b_slice_softmax<<<dim3(TS_M / 64, 8), 256, 0, stream>>>(XM, Wsl, bsl, temp, SWh, SWl);
    k2_pool<<<dim3(64, 32), 256, 0, stream>>>(FX, SWh, SWl, PART, PARTN);
    k2b_reduce<<<dim3(8, 32), 256, 0, stream>>>(PART, PARTN, ST, NORM);
    k3_attn<<<32, 64, 0, stream>>>(ST, NORM, Wqkv, OST);
    k3b_precomb<<<32, 256, 0, stream>>>(OST, Wout, Gth, Gtl);
    k4_gemm<<<2048, 256, 0, stream>>>(SWh, SWl, Gth, Gtl, bout, out);
}

// Round 14
// 660.104 us; speedup vs baseline: 1.0508x; 1.0508x over previous
//
#include <hip/hip_runtime.h>
#include <math.h>

// Problem constants: B=4, N=32768, D=256, H=8, S=64, DH=32
#define TS_N 32768
#define TS_M 131072   // B*N

typedef short bf16x8 __attribute__((ext_vector_type(8)));
typedef float f32x4  __attribute__((ext_vector_type(4)));
typedef unsigned short us4 __attribute__((ext_vector_type(4)));
typedef unsigned short us8 __attribute__((ext_vector_type(8)));

static __device__ __forceinline__ unsigned short f2bf(float f) {
    unsigned u = __float_as_uint(f);
    u = u + 0x7FFF + ((u >> 16) & 1);   // RNE
    return (unsigned short)(u >> 16);
}
static __device__ __forceinline__ float bf2f(unsigned short b) {
    return __uint_as_float(((unsigned)b) << 16);
}

// async global->LDS, 16B per lane; LDS dest = wave-uniform base + lane*16
#define GL16(gp, lp) __builtin_amdgcn_global_load_lds( \
    (const __attribute__((address_space(1))) unsigned int*)(gp), \
    (__attribute__((address_space(3))) unsigned int*)(lp), 16, 0, 0)

// ---------------------------------------------------------------------------
// K0w: convert + transpose Wfx, Wx -> Wt[w][n][k] bf16 hi/lo
// ---------------------------------------------------------------------------
__global__ __launch_bounds__(256) void k0_wt(
    const float* __restrict__ Wfx, const float* __restrict__ Wx,
    unsigned short* __restrict__ Wth, unsigned short* __restrict__ Wtl)
{
    const int n = blockIdx.x;       // 0..255 (output col of W = row of Wt)
    const int wsel = blockIdx.y;    // 0..1
    const int k = threadIdx.x;      // 0..255
    const float v = (wsel ? Wx : Wfx)[k * 256 + n];
    const unsigned short hh = f2bf(v);
    const int idx = (wsel * 256 + n) * 256 + k;
    Wth[idx] = hh;
    Wtl[idx] = f2bf(v - bf2f(hh));
}

// ---------------------------------------------------------------------------
// K1: FX/XM GEMM (R11-proven): reads x f32 directly, inline hi/lo split in
// A-staging; B via global_load_lds. Single-buffer 2-barrier K-loop (the m97
// structure; R12 showed explicit dbuf regresses). 4096 blocks, XCD-swizzled.
// ---------------------------------------------------------------------------
__global__ __launch_bounds__(256) void k1_gemm(
    const float* __restrict__ x,
    const unsigned short* __restrict__ Wth, const unsigned short* __restrict__ Wtl,
    const float* __restrict__ bfx, const float* __restrict__ bx,
    float* __restrict__ FX, float* __restrict__ XM)
{
    __shared__ unsigned short AldsH[4096];
    __shared__ unsigned short AldsL[4096];
    __shared__ unsigned short BldsH[4096];
    __shared__ unsigned short BldsL[4096];

    const int L = blockIdx.x;
    const int xcd = L & 7, ii = L >> 3;
    const int rb = xcd * 128 + (ii >> 2), nsel = ii & 3;
    const int row0 = rb * 128;
    const int n0 = (nsel & 1) * 128;
    const unsigned short* Bth = Wth + (nsel >> 1) * 65536 + n0 * 256;
    const unsigned short* Btl = Wtl + (nsel >> 1) * 65536 + n0 * 256;
    const float* bias = (nsel >> 1) ? bx : bfx;
    float* OUT = (nsel >> 1) ? XM : FX;

    const int t = threadIdx.x;
    const int w = t >> 6, l = t & 63;
    const int wm = w >> 1, wn = w & 1;
    const int lr = l & 15, lk = l >> 4;

    f32x4 acc[4][4];
#pragma unroll
    for (int i = 0; i < 4; ++i)
#pragma unroll
        for (int j = 0; j < 4; ++j) {
            acc[i][j][0] = 0.f; acc[i][j][1] = 0.f;
            acc[i][j][2] = 0.f; acc[i][j][3] = 0.f;
        }

    for (int step = 0; step < 8; ++step) {
        const int kk = step * 32;
        if (step > 0) __syncthreads();
#pragma unroll
        for (int g2i = 0; g2i < 2; ++g2i) {
            const int g2 = w + g2i * 4;                    // wave-uniform
            const size_t br = (size_t)(g2 * 16 + lr) * 256 + kk + lk * 8;
            const int lb = g2 * 512;                       // shorts
            GL16(Bth + br, BldsH + lb);
            GL16(Btl + br, BldsL + lb);
        }
#pragma unroll
        for (int g2i = 0; g2i < 2; ++g2i) {
            const int g2 = w + g2i * 4;
            const float* ap = &x[(size_t)(row0 + g2 * 16 + lr) * 256 + kk + lk * 8];
            float4 a0 = *(const float4*)ap;
            float4 a1 = *(const float4*)(ap + 4);
            float cc[8] = {a0.x, a0.y, a0.z, a0.w, a1.x, a1.y, a1.z, a1.w};
            us8 vh, vl;
#pragma unroll
            for (int j = 0; j < 8; ++j) {
                const unsigned short hb = f2bf(cc[j]);
                vh[j] = hb;
                vl[j] = f2bf(cc[j] - bf2f(hb));
            }
            *(us8*)&AldsH[(g2 * 64 + l) * 8] = vh;
            *(us8*)&AldsL[(g2 * 64 + l) * 8] = vl;
        }
        __syncthreads();

        bf16x8 ah[4], al[4], bh[4], bl[4];
#pragma unroll
        for (int g = 0; g < 4; ++g) {
            const int ac = (((wm * 4 + g) * 4 + lk) * 16 + lr) * 8;
            ah[g] = *(const bf16x8*)&AldsH[ac];
            al[g] = *(const bf16x8*)&AldsL[ac];
            const int bc = (((wn * 4 + g) * 4 + lk) * 16 + lr) * 8;
            bh[g] = *(const bf16x8*)&BldsH[bc];
            bl[g] = *(const bf16x8*)&BldsL[bc];
        }
#pragma unroll
        for (int m = 0; m < 4; ++m)
#pragma unroll
            for (int n = 0; n < 4; ++n) {
                acc[m][n] = __builtin_amdgcn_mfma_f32_16x16x32_bf16(ah[m], bh[n], acc[m][n], 0, 0, 0);
                acc[m][n] = __builtin_amdgcn_mfma_f32_16x16x32_bf16(ah[m], bl[n], acc[m][n], 0, 0, 0);
                acc[m][n] = __builtin_amdgcn_mfma_f32_16x16x32_bf16(al[m], bh[n], acc[m][n], 0, 0, 0);
            }
    }

    float bv[4];
#pragma unroll
    for (int n = 0; n < 4; ++n) bv[n] = bias[n0 + wn * 64 + n * 16 + lr];
#pragma unroll
    for (int m = 0; m < 4; ++m)
#pragma unroll
        for (int n = 0; n < 4; ++n) {
            const int col = n0 + wn * 64 + n * 16 + lr;
#pragma unroll
            for (int r = 0; r < 4; ++r) {
                const int row = row0 + wm * 64 + m * 16 + lk * 4 + r;
                OUT[(size_t)row * 256 + col] = acc[m][n][r] + bv[n];
            }
        }
}

// ---------------------------------------------------------------------------
// K2 (FUSED k1b+pool): grid (32 chunks x 32 bh), 1024 rows/chunk, 64-row
// slabs. Per slab: stage XM+FX head-slices -> in-block slice-logits+softmax
// (k1b's 4-thread/row pattern) -> SW to LDS + HBM (hi/lo) -> pooling accum.
// Eliminates the k1b dispatch and its 402 MB round-trip.
// ---------------------------------------------------------------------------
__global__ __launch_bounds__(256) void k2_pool(
    const float* __restrict__ FX, const float* __restrict__ XM,
    const float* __restrict__ Wsl, const float* __restrict__ bsl,
    const float* __restrict__ temp,
    unsigned short* __restrict__ SWh, unsigned short* __restrict__ SWl,
    float* __restrict__ PART, float* __restrict__ PARTN)
{
    __shared__ float XMs[64][36];
    __shared__ float FXs[64][36];
    __shared__ float SWs[64][68];
    __shared__ float Wsls[2048];     // W_slice [32][64] flat
    const int t = threadIdx.x;
    const int chunk = blockIdx.x;    // 0..31
    const int bh = blockIdx.y;       // 0..31
    const int b = bh >> 3, h = bh & 7;
    const int gbase = b * TS_N + chunk * 1024;

#pragma unroll
    for (int j = 0; j < 8; ++j) Wsls[j * 256 + t] = Wsl[j * 256 + t];
    const float invt = 1.0f / temp[h];

    const int rs = t >> 2, cq = (t & 3) * 8;   // staging: row rs, cols cq..cq+7
    float4 xm0, xm1, fx0, fx1;
    {
        const size_t base = (size_t)(gbase + rs) * 256 + h * 32 + cq;
        xm0 = *(const float4*)&XM[base];
        xm1 = *(const float4*)&XM[base + 4];
        fx0 = *(const float4*)&FX[base];
        fx1 = *(const float4*)&FX[base + 4];
    }

    const int c = t & 31, sb2 = (t >> 5) * 8;  // pooling mapping
    const int row = t >> 2, p = t & 3;         // softmax mapping
    float acc[8];
#pragma unroll
    for (int j = 0; j < 8; ++j) acc[j] = 0.f;
    float accn = 0.f;

    for (int s = 0; s < 16; ++s) {
        // publish staged slab
        *(float4*)&XMs[rs][cq]     = xm0;
        *(float4*)&XMs[rs][cq + 4] = xm1;
        *(float4*)&FXs[rs][cq]     = fx0;
        *(float4*)&FXs[rs][cq + 4] = fx1;
        __syncthreads();   // XMs/FXs (and Wsls on s=0) ready
        // prefetch next slab (lands under softmax+pooling)
        if (s < 15) {
            const size_t base = (size_t)(gbase + (s + 1) * 64 + rs) * 256 + h * 32 + cq;
            xm0 = *(const float4*)&XM[base];
            xm1 = *(const float4*)&XM[base + 4];
            fx0 = *(const float4*)&FX[base];
            fx1 = *(const float4*)&FX[base + 4];
        }

        // ---- softmax: 4 threads/row, 16 slices each ----
        float xm[32];
#pragma unroll
        for (int c2 = 0; c2 < 32; ++c2) xm[c2] = XMs[row][c2];
        float v[16];
        float mx = -1e30f;
#pragma unroll
        for (int q = 0; q < 4; ++q) {
            float4 a = *(const float4*)&bsl[p * 16 + q * 4];
#pragma unroll
            for (int c2 = 0; c2 < 32; ++c2) {
                const float4 wv = *(const float4*)&Wsls[c2 * 64 + p * 16 + q * 4];
                a.x = fmaf(xm[c2], wv.x, a.x);
                a.y = fmaf(xm[c2], wv.y, a.y);
                a.z = fmaf(xm[c2], wv.z, a.z);
                a.w = fmaf(xm[c2], wv.w, a.w);
            }
            float v0 = a.x * invt, v1 = a.y * invt, v2 = a.z * invt, v3 = a.w * invt;
            v[q * 4 + 0] = v0; v[q * 4 + 1] = v1;
            v[q * 4 + 2] = v2; v[q * 4 + 3] = v3;
            mx = fmaxf(mx, fmaxf(fmaxf(v0, v1), fmaxf(v2, v3)));
        }
        mx = fmaxf(mx, __shfl_xor(mx, 1));
        mx = fmaxf(mx, __shfl_xor(mx, 2));
        float sum = 0.f;
#pragma unroll
        for (int i = 0; i < 16; ++i) { v[i] = expf(v[i] - mx); sum += v[i]; }
        sum += __shfl_xor(sum, 1);
        sum += __shfl_xor(sum, 2);
        const float inv = 1.0f / sum;
        // SW -> LDS (pooling) + HBM hi/lo (k4)
        us8 oh0, oh1, ol0, ol1;
#pragma unroll
        for (int j = 0; j < 8; ++j) {
            const float o = v[j] * inv;
            SWs[row][p * 16 + j] = o;
            const unsigned short hb = f2bf(o);
            oh0[j] = hb; ol0[j] = f2bf(o - bf2f(hb));
        }
#pragma unroll
        for (int j = 0; j < 8; ++j) {
            const float o = v[8 + j] * inv;
            SWs[row][p * 16 + 8 + j] = o;
            const unsigned short hb = f2bf(o);
            oh1[j] = hb; ol1[j] = f2bf(o - bf2f(hb));
        }
        const size_t gsw = (size_t)(gbase + s * 64 + row) * 512 + h * 64 + p * 16;
        *(us8*)&SWh[gsw]     = oh0;
        *(us8*)&SWh[gsw + 8] = oh1;
        *(us8*)&SWl[gsw]     = ol0;
        *(us8*)&SWl[gsw + 8] = ol1;
        __syncthreads();   // SWs ready

        // ---- pooling accumulation ----
#pragma unroll 8
        for (int rr = 0; rr < 64; ++rr) {
            const float f = FXs[rr][c];
            float4 s0 = *(const float4*)&SWs[rr][sb2];
            float4 s1 = *(const float4*)&SWs[rr][sb2 + 4];
            acc[0] = fmaf(f, s0.x, acc[0]); acc[1] = fmaf(f, s0.y, acc[1]);
            acc[2] = fmaf(f, s0.z, acc[2]); acc[3] = fmaf(f, s0.w, acc[3]);
            acc[4] = fmaf(f, s1.x, acc[4]); acc[5] = fmaf(f, s1.y, acc[5]);
            acc[6] = fmaf(f, s1.z, acc[6]); acc[7] = fmaf(f, s1.w, acc[7]);
        }
        if (t < 64) {
#pragma unroll 8
            for (int rr = 0; rr < 64; ++rr) accn += SWs[rr][t];
        }
        __syncthreads();   // pooling done: safe to overwrite LDS next slab
    }

    const int pbase = (bh * 32 + chunk) * 2048;
#pragma unroll
    for (int j = 0; j < 8; ++j) PART[pbase + (sb2 + j) * 32 + c] = acc[j];
    if (t < 64) PARTN[(bh * 32 + chunk) * 64 + t] = accn;
}

// ---------------------------------------------------------------------------
// K2b: deterministic reduce of 32 chunk partials. Grid (8 groups x 32 bh).
// ---------------------------------------------------------------------------
__global__ __launch_bounds__(256) void k2b_reduce(
    const float* __restrict__ PART, const float* __restrict__ PARTN,
    float* __restrict__ ST, float* __restrict__ NORM)
{
    const int g = blockIdx.x, bh = blockIdx.y, t = threadIdx.x;
    const int e = g * 256 + t;
    float s = 0.f;
    for (int ch = 0; ch < 32; ++ch) s += PART[(size_t)(bh * 32 + ch) * 2048 + e];
    ST[bh * 2048 + e] = s;
    if (g == 0 && t < 64) {
        float sn = 0.f;
        for (int ch = 0; ch < 32; ++ch) sn += PARTN[(bh * 32 + ch) * 64 + t];
        NORM[bh * 64 + t] = sn;
    }
}

// ---------------------------------------------------------------------------
// K3: tiny attention among 64 slice tokens per (b,h). 1 wave per block.
// ---------------------------------------------------------------------------
__global__ __launch_bounds__(64) void k3_attn(
    const float* __restrict__ ST, const float* __restrict__ NORM,
    const float* __restrict__ Wqkv, float* __restrict__ OST)
{
    __shared__ float Wq[32 * 96];
    __shared__ float Kl[64][32];
    __shared__ float Vl[64][32];
    __shared__ float Dl[64][68];
    const int bh = blockIdx.x;
    const int s  = threadIdx.x;

    for (int i = 0; i < 48; ++i) Wq[i * 64 + s] = Wqkv[i * 64 + s];
    float st[32];
    const float nrm = NORM[bh * 64 + s] + 1e-5f;
#pragma unroll
    for (int c = 0; c < 32; ++c) st[c] = ST[bh * 2048 + s * 32 + c] / nrm;
    __syncthreads();

    float q[32];
#pragma unroll
    for (int o4 = 0; o4 < 8; ++o4) {
        float ax = 0.f, ay = 0.f, az = 0.f, aw = 0.f;
#pragma unroll
        for (int c = 0; c < 32; ++c) {
            float4 w = *(const float4*)&Wq[c * 96 + o4 * 4];
            ax = fmaf(st[c], w.x, ax); ay = fmaf(st[c], w.y, ay);
            az = fmaf(st[c], w.z, az); aw = fmaf(st[c], w.w, aw);
        }
        q[o4 * 4 + 0] = ax; q[o4 * 4 + 1] = ay; q[o4 * 4 + 2] = az; q[o4 * 4 + 3] = aw;
    }
#pragma unroll
    for (int o4 = 0; o4 < 8; ++o4) {
        float ax = 0.f, ay = 0.f, az = 0.f, aw = 0.f;
#pragma unroll
        for (int c = 0; c < 32; ++c) {
            float4 w = *(const float4*)&Wq[c * 96 + 32 + o4 * 4];
            ax = fmaf(st[c], w.x, ax); ay = fmaf(st[c], w.y, ay);
            az = fmaf(st[c], w.z, az); aw = fmaf(st[c], w.w, aw);
        }
        float4 kv; kv.x = ax; kv.y = ay; kv.z = az; kv.w = aw;
        *(float4*)&Kl[s][o4 * 4] = kv;
    }
#pragma unroll
    for (int o4 = 0; o4 < 8; ++o4) {
        float ax = 0.f, ay = 0.f, az = 0.f, aw = 0.f;
#pragma unroll
        for (int c = 0; c < 32; ++c) {
            float4 w = *(const float4*)&Wq[c * 96 + 64 + o4 * 4];
            ax = fmaf(st[c], w.x, ax); ay = fmaf(st[c], w.y, ay);
            az = fmaf(st[c], w.z, az); aw = fmaf(st[c], w.w, aw);
        }
        float4 vv; vv.x = ax; vv.y = ay; vv.z = az; vv.w = aw;
        *(float4*)&Vl[s][o4 * 4] = vv;
    }
    __syncthreads();

    const float scale = 0.17677669529663687f;  // 32^-0.5
    float mx = -1e30f;
    for (int t2 = 0; t2 < 64; ++t2) {
        float d = 0.f;
#pragma unroll
        for (int c4 = 0; c4 < 8; ++c4) {
            float4 kv = *(const float4*)&Kl[t2][c4 * 4];
            d = fmaf(q[c4 * 4 + 0], kv.x, d); d = fmaf(q[c4 * 4 + 1], kv.y, d);
            d = fmaf(q[c4 * 4 + 2], kv.z, d); d = fmaf(q[c4 * 4 + 3], kv.w, d);
        }
        d *= scale;
        Dl[s][t2] = d;
        mx = fmaxf(mx, d);
    }
    float sum = 0.f;
    for (int t2 = 0; t2 < 64; ++t2) { float e = expf(Dl[s][t2] - mx); Dl[s][t2] = e; sum += e; }
    const float inv = 1.0f / sum;
    float out[32];
#pragma unroll
    for (int c = 0; c < 32; ++c) out[c] = 0.f;
    for (int t2 = 0; t2 < 64; ++t2) {
        const float p = Dl[s][t2] * inv;
#pragma unroll
        for (int c4 = 0; c4 < 8; ++c4) {
            float4 vv = *(const float4*)&Vl[t2][c4 * 4];
            out[c4 * 4 + 0] = fmaf(p, vv.x, out[c4 * 4 + 0]);
            out[c4 * 4 + 1] = fmaf(p, vv.y, out[c4 * 4 + 1]);
            out[c4 * 4 + 2] = fmaf(p, vv.z, out[c4 * 4 + 2]);
            out[c4 * 4 + 3] = fmaf(p, vv.w, out[c4 * 4 + 3]);
        }
    }
#pragma unroll
    for (int c4 = 0; c4 < 8; ++c4) {
        float4 ov;
        ov.x = out[c4 * 4 + 0]; ov.y = out[c4 * 4 + 1];
        ov.z = out[c4 * 4 + 2]; ov.w = out[c4 * 4 + 3];
        *(float4*)&OST[bh * 2048 + s * 32 + c4 * 4] = ov;
    }
}

// ---------------------------------------------------------------------------
// K3b: G[b, h*64+s, :] = OST[bh,s,:] @ Wout[h*32:(h+1)*32, :], written
// TRANSPOSED as bf16 hi/lo: Gt[b][n=256][k=512].
// ---------------------------------------------------------------------------
__global__ __launch_bounds__(256) void k3b_precomb(
    const float* __restrict__ OST, const float* __restrict__ Wout,
    unsigned short* __restrict__ Gth, unsigned short* __restrict__ Gtl)
{
    __shared__ float OSTs[64][36];   // [s][c], padded
    __shared__ float Wc[32][256];    // [c][o]
    const int bh = blockIdx.x;
    const int b = bh >> 3, h = bh & 7;
    const int t = threadIdx.x;

#pragma unroll
    for (int j = 0; j < 2; ++j) {
        const int e = (j * 256 + t) * 4;       // 0..2044, step 4
        float4 v = *(const float4*)&OST[bh * 2048 + e];
        const int s = e >> 5, c = e & 31;
        OSTs[s][c + 0] = v.x; OSTs[s][c + 1] = v.y;
        OSTs[s][c + 2] = v.z; OSTs[s][c + 3] = v.w;
    }
#pragma unroll
    for (int j = 0; j < 8; ++j) {
        const int e = (j * 256 + t) * 4;       // 0..8188
        const int c = e >> 8, o = e & 255;
        *(float4*)&Wc[c][o] = *(const float4*)&Wout[(h * 32 + c) * 256 + o];
    }
    __syncthreads();

    float wcol[32];
#pragma unroll
    for (int c = 0; c < 32; ++c) wcol[c] = Wc[c][t];

    for (int s = 0; s < 64; ++s) {
        float a = 0.f;
#pragma unroll
        for (int c = 0; c < 32; ++c) a = fmaf(OSTs[s][c], wcol[c], a);
        const unsigned short gh = f2bf(a);
        const size_t idx = ((size_t)(b * 256 + t)) * 512 + h * 64 + s;
        Gth[idx] = gh;
        Gtl[idx] = f2bf(a - bf2f(gh));
    }
}

// ---------------------------------------------------------------------------
// K4: out = SW[131072x512] @ Gt_b^T + bout. 2048 blocks, XCD-swizzled pairs.
// R11-proven single-buffer staged split-bf16 body, K=512.
// ---------------------------------------------------------------------------
__global__ __launch_bounds__(256) void k4_gemm(
    const unsigned short* __restrict__ SWh, const unsigned short* __restrict__ SWl,
    const unsigned short* __restrict__ Gth, const unsigned short* __restrict__ Gtl,
    const float* __restrict__ bout, float* __restrict__ out)
{
    __shared__ unsigned short Alds[2][128 * 32];
    __shared__ unsigned short Blds[2][128 * 32];
    const int L = blockIdx.x;
    const int xcd = L & 7, ii = L >> 3;
    const int rb = xcd * 128 + (ii >> 1), nsel = ii & 1;
    const int row0 = rb * 128;
    const int n0 = nsel * 128;
    const int b = row0 >> 15;
    const unsigned short* Bth = Gth + ((size_t)b * 256 + n0) * 512;
    const unsigned short* Btl = Gtl + ((size_t)b * 256 + n0) * 512;

    const int t = threadIdx.x;
    const int w = t >> 6, l = t & 63;
    const int wm = w >> 1, wn = w & 1;
    const int lr = l & 15, lk = l >> 4;

    f32x4 acc[4][4];
#pragma unroll
    for (int i = 0; i < 4; ++i)
#pragma unroll
        for (int j = 0; j < 4; ++j) {
            acc[i][j][0] = 0.f; acc[i][j][1] = 0.f;
            acc[i][j][2] = 0.f; acc[i][j][3] = 0.f;
        }

    for (int step = 0; step < 16; ++step) {
        const int kk = step * 32;
        if (step > 0) __syncthreads();
#pragma unroll
        for (int g2i = 0; g2i < 2; ++g2i) {
            const int g2 = w + g2i * 4;
            const size_t ar = (size_t)(row0 + g2 * 16 + lr) * 512 + kk + lk * 8;
            const size_t br = (size_t)(g2 * 16 + lr) * 512 + kk + lk * 8;
            const int lb = g2 * 512;
            GL16(SWh + ar, &Alds[0][lb]);
            GL16(SWl + ar, &Alds[1][lb]);
            GL16(Bth + br, &Blds[0][lb]);
            GL16(Btl + br, &Blds[1][lb]);
        }
        __syncthreads();

        bf16x8 ah[4], al[4], bh[4], bl[4];
#pragma unroll
        for (int g = 0; g < 4; ++g) {
            const int ac = (((wm * 4 + g) * 4 + lk) * 16 + lr) * 8;
            ah[g] = *(const bf16x8*)&Alds[0][ac];
            al[g] = *(const bf16x8*)&Alds[1][ac];
            const int bc = (((wn * 4 + g) * 4 + lk) * 16 + lr) * 8;
            bh[g] = *(const bf16x8*)&Blds[0][bc];
            bl[g] = *(const bf16x8*)&Blds[1][bc];
        }
#pragma unroll
        for (int m = 0; m < 4; ++m)
#pragma unroll
            for (int n = 0; n < 4; ++n) {
                acc[m][n] = __builtin_amdgcn_mfma_f32_16x16x32_bf16(ah[m], bh[n], acc[m][n], 0, 0, 0);
                acc[m][n] = __builtin_amdgcn_mfma_f32_16x16x32_bf16(ah[m], bl[n], acc[m][n], 0, 0, 0);
                acc[m][n] = __builtin_amdgcn_mfma_f32_16x16x32_bf16(al[m], bh[n], acc[m][n], 0, 0, 0);
            }
    }

    float bv[4];
#pragma unroll
    for (int n = 0; n < 4; ++n) bv[n] = bout[n0 + wn * 64 + n * 16 + lr];
#pragma unroll
    for (int m = 0; m < 4; ++m)
#pragma unroll
        for (int n = 0; n < 4; ++n) {
            const int col = n0 + wn * 64 + n * 16 + lr;
#pragma unroll
            for (int r = 0; r < 4; ++r) {
                const int row = row0 + wm * 64 + m * 16 + lk * 4 + r;
                out[(size_t)row * 256 + col] = acc[m][n][r] + bv[n];
            }
        }
}

extern "C" void kernel_launch(void* const* d_in, const int* in_sizes, int n_in,
                              void* d_out, int out_size, void* d_ws, size_t ws_size,
                              hipStream_t stream) {
    (void)in_sizes; (void)n_in; (void)out_size; (void)ws_size;
    const float* x    = (const float*)d_in[0];
    const float* Wfx  = (const float*)d_in[1];
    const float* bfx  = (const float*)d_in[2];
    const float* Wx   = (const float*)d_in[3];
    const float* bx   = (const float*)d_in[4];
    const float* Wsl  = (const float*)d_in[5];
    const float* bsl  = (const float*)d_in[6];
    const float* temp = (const float*)d_in[7];
    const float* Wqkv = (const float*)d_in[8];
    const float* Wout = (const float*)d_in[9];
    const float* bout = (const float*)d_in[10];
    float* out = (float*)d_out;
    char* w = (char*)d_ws;

    // ws layout (bytes) - XM stays LIVE through k2 (fused kernel reads it),
    // so PART/PARTN get their own region:
    // [0, 128M):       XM f32
    // [128M, 384M):    SWh | SWl
    // [384M+, ...):    ST/NORM/OST/Gt/Wt/PART/PARTN  (~28 MB)
    float* XM = (float*)w;
    unsigned short* SWh = (unsigned short*)(w + 134217728);
    unsigned short* SWl = SWh + 67108864;
    char* p = w + 134217728 + 268435456;
    float* ST    = (float*)p;            p += 262144;      // 65,536 f
    float* NORM  = (float*)p;            p += 8192;        // 2,048 f
    float* OST   = (float*)p;            p += 262144;      // 65,536 f
    unsigned short* Gth = (unsigned short*)p; p += 1048576; // 524,288 us
    unsigned short* Gtl = (unsigned short*)p; p += 1048576;
    unsigned short* Wth = (unsigned short*)p; p += 262144;  // 131,072 us
    unsigned short* Wtl = (unsigned short*)p; p += 262144;
    float* PART  = (float*)p;            p += 8388608;     // 2,097,152 f
    float* PARTN = (float*)p;            p += 262144;      // 65,536 f
    float* FX = out;   // d_out doubles as FX scratch (read by k2, overwritten by k4)

    k0_wt<<<dim3(256, 2), 256, 0, stream>>>(Wfx, Wx, Wth, Wtl);
    k1_gemm<<<4096, 256, 0, stream>>>(x, Wth, Wtl, bfx, bx, FX, XM);
    k2_pool<<<dim3(32, 32), 256, 0, stream>>>(FX, XM, Wsl, bsl, temp,
                                              SWh, SWl, PART, PARTN);
    k2b_reduce<<<dim3(8, 32), 256, 0, stream>>>(PART, PARTN, ST, NORM);
    k3_attn<<<32, 64, 0, stream>>>(ST, NORM, Wqkv, OST);
    k3b_precomb<<<32, 256, 0, stream>>>(OST, Wout, Gth, Gtl);
    k4_gemm<<<2048, 256, 0, stream>>>(SWh, SWl, Gth, Gtl, bout, out);
}

// Round 15
// 609.658 us; speedup vs baseline: 1.1378x; 1.0827x over previous
//
#include <hip/hip_runtime.h>
#include <math.h>

// Problem constants: B=4, N=32768, D=256, H=8, S=64, DH=32
#define TS_N 32768
#define TS_M 131072   // B*N

typedef short bf16x8 __attribute__((ext_vector_type(8)));
typedef float f32x4  __attribute__((ext_vector_type(4)));
typedef unsigned short us4 __attribute__((ext_vector_type(4)));
typedef unsigned short us8 __attribute__((ext_vector_type(8)));

static __device__ __forceinline__ unsigned short f2bf(float f) {
    unsigned u = __float_as_uint(f);
    u = u + 0x7FFF + ((u >> 16) & 1);   // RNE
    return (unsigned short)(u >> 16);
}
static __device__ __forceinline__ float bf2f(unsigned short b) {
    return __uint_as_float(((unsigned)b) << 16);
}

// async global->LDS, 16B per lane; LDS dest = wave-uniform base + lane*16
#define GL16(gp, lp) __builtin_amdgcn_global_load_lds( \
    (const __attribute__((address_space(1))) unsigned int*)(gp), \
    (__attribute__((address_space(3))) unsigned int*)(lp), 16, 0, 0)

// ---------------------------------------------------------------------------
// K0w: convert + transpose Wfx, Wx -> Wt[w][n][k] bf16 hi/lo
// ---------------------------------------------------------------------------
__global__ __launch_bounds__(256) void k0_wt(
    const float* __restrict__ Wfx, const float* __restrict__ Wx,
    unsigned short* __restrict__ Wth, unsigned short* __restrict__ Wtl)
{
    const int n = blockIdx.x;       // 0..255 (output col of W = row of Wt)
    const int wsel = blockIdx.y;    // 0..1
    const int k = threadIdx.x;      // 0..255
    const float v = (wsel ? Wx : Wfx)[k * 256 + n];
    const unsigned short hh = f2bf(v);
    const int idx = (wsel * 256 + n) * 256 + k;
    Wth[idx] = hh;
    Wtl[idx] = f2bf(v - bf2f(hh));
}

// ---------------------------------------------------------------------------
// K1: FX/XM GEMM (R11-proven): reads x f32 directly, inline hi/lo split in
// A-staging; B via global_load_lds. Single-buffer 2-barrier K-loop (m97
// structure; R12 showed explicit dbuf regresses). 4096 blocks, XCD-swizzled.
// ---------------------------------------------------------------------------
__global__ __launch_bounds__(256) void k1_gemm(
    const float* __restrict__ x,
    const unsigned short* __restrict__ Wth, const unsigned short* __restrict__ Wtl,
    const float* __restrict__ bfx, const float* __restrict__ bx,
    float* __restrict__ FX, float* __restrict__ XM)
{
    __shared__ unsigned short AldsH[4096];
    __shared__ unsigned short AldsL[4096];
    __shared__ unsigned short BldsH[4096];
    __shared__ unsigned short BldsL[4096];

    const int L = blockIdx.x;
    const int xcd = L & 7, ii = L >> 3;
    const int rb = xcd * 128 + (ii >> 2), nsel = ii & 3;
    const int row0 = rb * 128;
    const int n0 = (nsel & 1) * 128;
    const unsigned short* Bth = Wth + (nsel >> 1) * 65536 + n0 * 256;
    const unsigned short* Btl = Wtl + (nsel >> 1) * 65536 + n0 * 256;
    const float* bias = (nsel >> 1) ? bx : bfx;
    float* OUT = (nsel >> 1) ? XM : FX;

    const int t = threadIdx.x;
    const int w = t >> 6, l = t & 63;
    const int wm = w >> 1, wn = w & 1;
    const int lr = l & 15, lk = l >> 4;

    f32x4 acc[4][4];
#pragma unroll
    for (int i = 0; i < 4; ++i)
#pragma unroll
        for (int j = 0; j < 4; ++j) {
            acc[i][j][0] = 0.f; acc[i][j][1] = 0.f;
            acc[i][j][2] = 0.f; acc[i][j][3] = 0.f;
        }

    for (int step = 0; step < 8; ++step) {
        const int kk = step * 32;
        if (step > 0) __syncthreads();
#pragma unroll
        for (int g2i = 0; g2i < 2; ++g2i) {
            const int g2 = w + g2i * 4;                    // wave-uniform
            const size_t br = (size_t)(g2 * 16 + lr) * 256 + kk + lk * 8;
            const int lb = g2 * 512;                       // shorts
            GL16(Bth + br, BldsH + lb);
            GL16(Btl + br, BldsL + lb);
        }
#pragma unroll
        for (int g2i = 0; g2i < 2; ++g2i) {
            const int g2 = w + g2i * 4;
            const float* ap = &x[(size_t)(row0 + g2 * 16 + lr) * 256 + kk + lk * 8];
            float4 a0 = *(const float4*)ap;
            float4 a1 = *(const float4*)(ap + 4);
            float cc[8] = {a0.x, a0.y, a0.z, a0.w, a1.x, a1.y, a1.z, a1.w};
            us8 vh, vl;
#pragma unroll
            for (int j = 0; j < 8; ++j) {
                const unsigned short hb = f2bf(cc[j]);
                vh[j] = hb;
                vl[j] = f2bf(cc[j] - bf2f(hb));
            }
            *(us8*)&AldsH[(g2 * 64 + l) * 8] = vh;
            *(us8*)&AldsL[(g2 * 64 + l) * 8] = vl;
        }
        __syncthreads();

        bf16x8 ah[4], al[4], bh[4], bl[4];
#pragma unroll
        for (int g = 0; g < 4; ++g) {
            const int ac = (((wm * 4 + g) * 4 + lk) * 16 + lr) * 8;
            ah[g] = *(const bf16x8*)&AldsH[ac];
            al[g] = *(const bf16x8*)&AldsL[ac];
            const int bc = (((wn * 4 + g) * 4 + lk) * 16 + lr) * 8;
            bh[g] = *(const bf16x8*)&BldsH[bc];
            bl[g] = *(const bf16x8*)&BldsL[bc];
        }
#pragma unroll
        for (int m = 0; m < 4; ++m)
#pragma unroll
            for (int n = 0; n < 4; ++n) {
                acc[m][n] = __builtin_amdgcn_mfma_f32_16x16x32_bf16(ah[m], bh[n], acc[m][n], 0, 0, 0);
                acc[m][n] = __builtin_amdgcn_mfma_f32_16x16x32_bf16(ah[m], bl[n], acc[m][n], 0, 0, 0);
                acc[m][n] = __builtin_amdgcn_mfma_f32_16x16x32_bf16(al[m], bh[n], acc[m][n], 0, 0, 0);
            }
    }

    float bv[4];
#pragma unroll
    for (int n = 0; n < 4; ++n) bv[n] = bias[n0 + wn * 64 + n * 16 + lr];
#pragma unroll
    for (int m = 0; m < 4; ++m)
#pragma unroll
        for (int n = 0; n < 4; ++n) {
            const int col = n0 + wn * 64 + n * 16 + lr;
#pragma unroll
            for (int r = 0; r < 4; ++r) {
                const int row = row0 + wm * 64 + m * 16 + lk * 4 + r;
                OUT[(size_t)row * 256 + col] = acc[m][n][r] + bv[n];
            }
        }
}

// ---------------------------------------------------------------------------
// K1b: logits = XM_head @ W_slice + b_slice, /temp[h], softmax over S=64.
// Writes SW as f32 [M][512] (k4 splits to hi/lo during its A-staging).
// ---------------------------------------------------------------------------
__global__ __launch_bounds__(256) void k1b_slice_softmax(
    const float* __restrict__ XM, const float* __restrict__ Wsl,
    const float* __restrict__ bsl, const float* __restrict__ temp,
    float* __restrict__ SW)
{
    __shared__ float XMs[32][68];  // [c][m]
    __shared__ float Ws[32][68];   // [c][s]
    __shared__ float Ls[64][68];   // logits tile [row][s]
    const int t  = threadIdx.x;
    const int r0 = blockIdx.x * 64;
    const int h  = blockIdx.y;

    {
        const int m = t >> 2, cq = (t & 3) * 8;
        float4 v0 = *(const float4*)&XM[(size_t)(r0 + m) * 256 + h * 32 + cq];
        float4 v1 = *(const float4*)&XM[(size_t)(r0 + m) * 256 + h * 32 + cq + 4];
        XMs[cq + 0][m] = v0.x; XMs[cq + 1][m] = v0.y; XMs[cq + 2][m] = v0.z; XMs[cq + 3][m] = v0.w;
        XMs[cq + 4][m] = v1.x; XMs[cq + 5][m] = v1.y; XMs[cq + 6][m] = v1.z; XMs[cq + 7][m] = v1.w;
        const int wk = t >> 3, wn = (t & 7) * 8;
        float4 u0 = *(const float4*)&Wsl[wk * 64 + wn];
        float4 u1 = *(const float4*)&Wsl[wk * 64 + wn + 4];
        *(float4*)&Ws[wk][wn]     = u0;
        *(float4*)&Ws[wk][wn + 4] = u1;
    }
    __syncthreads();

    const int tx = t & 15, ty = t >> 4;
    float acc[4][4];
#pragma unroll
    for (int i = 0; i < 4; ++i)
#pragma unroll
        for (int j = 0; j < 4; ++j) acc[i][j] = 0.f;
#pragma unroll
    for (int c = 0; c < 32; ++c) {
        float4 av = *(const float4*)&XMs[c][ty * 4];
        float4 bv = *(const float4*)&Ws[c][tx * 4];
        float a_[4] = {av.x, av.y, av.z, av.w};
        float b_[4] = {bv.x, bv.y, bv.z, bv.w};
#pragma unroll
        for (int i = 0; i < 4; ++i)
#pragma unroll
            for (int j = 0; j < 4; ++j)
                acc[i][j] = fmaf(a_[i], b_[j], acc[i][j]);
    }
    const float invt = 1.0f / temp[h];
#pragma unroll
    for (int i = 0; i < 4; ++i)
#pragma unroll
        for (int j = 0; j < 4; ++j)
            Ls[ty * 4 + i][tx * 4 + j] = (acc[i][j] + bsl[tx * 4 + j]) * invt;
    __syncthreads();

    const int row = t >> 2, j4 = t & 3;
    float v[16];
    float mx = -1e30f;
#pragma unroll
    for (int i = 0; i < 16; ++i) { v[i] = Ls[row][j4 * 16 + i]; mx = fmaxf(mx, v[i]); }
    mx = fmaxf(mx, __shfl_xor(mx, 1));
    mx = fmaxf(mx, __shfl_xor(mx, 2));
    float sum = 0.f;
#pragma unroll
    for (int i = 0; i < 16; ++i) { v[i] = expf(v[i] - mx); sum += v[i]; }
    sum += __shfl_xor(sum, 1);
    sum += __shfl_xor(sum, 2);
    const float inv = 1.0f / sum;
#pragma unroll
    for (int q = 0; q < 4; ++q) {
        float4 ov;
        ov.x = v[q * 4 + 0] * inv; ov.y = v[q * 4 + 1] * inv;
        ov.z = v[q * 4 + 2] * inv; ov.w = v[q * 4 + 3] * inv;
        *(float4*)&SW[(size_t)(r0 + row) * 512 + h * 64 + j4 * 16 + q * 4] = ov;
    }
}

// ---------------------------------------------------------------------------
// K2: partial pooling (R11 structure). Grid (64 chunks x 32 bh), 512 rows.
// SW read as f32 directly (no hi/lo reconstruct).
// ---------------------------------------------------------------------------
__global__ __launch_bounds__(256) void k2_pool(
    const float* __restrict__ FX, const float* __restrict__ SW,
    float* __restrict__ PART, float* __restrict__ PARTN)
{
    __shared__ float SWs[2][64][68];
    __shared__ float FXs[2][64][36];
    const int t = threadIdx.x;
    const int chunk = blockIdx.x;   // 0..63
    const int bh = blockIdx.y;      // 0..31
    const int b = bh >> 3, h = bh & 7;
    const int gbase = b * TS_N + chunk * 512;

    const int rs = t >> 2;          // staging row 0..63
    const int ch0 = t & 3;          // staging chunk: ch0 and ch0+4

    float4 swr[4];
    float4 fxr[2];

    {
        const size_t swbase = (size_t)(gbase + rs) * 512 + h * 64;
        swr[0] = *(const float4*)&SW[swbase + ch0 * 8];
        swr[1] = *(const float4*)&SW[swbase + ch0 * 8 + 4];
        swr[2] = *(const float4*)&SW[swbase + (ch0 + 4) * 8];
        swr[3] = *(const float4*)&SW[swbase + (ch0 + 4) * 8 + 4];
        const size_t fxbase = (size_t)(gbase + rs) * 256 + h * 32;
        fxr[0] = *(const float4*)&FX[fxbase + ch0 * 4];
        fxr[1] = *(const float4*)&FX[fxbase + (ch0 + 4) * 4];
    }

    const int c = t & 31, sb = (t >> 5) * 8;
    float acc[8];
#pragma unroll
    for (int j = 0; j < 8; ++j) acc[j] = 0.f;
    float accn = 0.f;
    int buf = 0;

    for (int s = 0; s < 8; ++s) {
        *(float4*)&SWs[buf][rs][ch0 * 8]           = swr[0];
        *(float4*)&SWs[buf][rs][ch0 * 8 + 4]       = swr[1];
        *(float4*)&SWs[buf][rs][(ch0 + 4) * 8]     = swr[2];
        *(float4*)&SWs[buf][rs][(ch0 + 4) * 8 + 4] = swr[3];
        *(float4*)&FXs[buf][rs][ch0 * 4]       = fxr[0];
        *(float4*)&FXs[buf][rs][(ch0 + 4) * 4] = fxr[1];
        __syncthreads();
        if (s < 7) {
            const int g2 = gbase + (s + 1) * 64 + rs;
            const size_t swbase = (size_t)g2 * 512 + h * 64;
            swr[0] = *(const float4*)&SW[swbase + ch0 * 8];
            swr[1] = *(const float4*)&SW[swbase + ch0 * 8 + 4];
            swr[2] = *(const float4*)&SW[swbase + (ch0 + 4) * 8];
            swr[3] = *(const float4*)&SW[swbase + (ch0 + 4) * 8 + 4];
            const size_t fxbase = (size_t)g2 * 256 + h * 32;
            fxr[0] = *(const float4*)&FX[fxbase + ch0 * 4];
            fxr[1] = *(const float4*)&FX[fxbase + (ch0 + 4) * 4];
        }
#pragma unroll 8
        for (int rr = 0; rr < 64; ++rr) {
            const float f = FXs[buf][rr][c];
            float4 s0 = *(const float4*)&SWs[buf][rr][sb];
            float4 s1 = *(const float4*)&SWs[buf][rr][sb + 4];
            acc[0] = fmaf(f, s0.x, acc[0]); acc[1] = fmaf(f, s0.y, acc[1]);
            acc[2] = fmaf(f, s0.z, acc[2]); acc[3] = fmaf(f, s0.w, acc[3]);
            acc[4] = fmaf(f, s1.x, acc[4]); acc[5] = fmaf(f, s1.y, acc[5]);
            acc[6] = fmaf(f, s1.z, acc[6]); acc[7] = fmaf(f, s1.w, acc[7]);
        }
        if (t < 64) {
#pragma unroll 8
            for (int rr = 0; rr < 64; ++rr) accn += SWs[buf][rr][t];
        }
        buf ^= 1;
    }

    const int pbase = (bh * 64 + chunk) * 2048;
#pragma unroll
    for (int j = 0; j < 8; ++j) PART[pbase + (sb + j) * 32 + c] = acc[j];
    if (t < 64) PARTN[(bh * 64 + chunk) * 64 + t] = accn;
}

// ---------------------------------------------------------------------------
// K2b: deterministic reduce of 64 chunk partials. Grid (8 groups x 32 bh).
// ---------------------------------------------------------------------------
__global__ __launch_bounds__(256) void k2b_reduce(
    const float* __restrict__ PART, const float* __restrict__ PARTN,
    float* __restrict__ ST, float* __restrict__ NORM)
{
    const int g = blockIdx.x, bh = blockIdx.y, t = threadIdx.x;
    const int e = g * 256 + t;
    float s = 0.f;
    for (int ch = 0; ch < 64; ++ch) s += PART[(size_t)(bh * 64 + ch) * 2048 + e];
    ST[bh * 2048 + e] = s;
    if (g == 0 && t < 64) {
        float sn = 0.f;
        for (int ch = 0; ch < 64; ++ch) sn += PARTN[(bh * 64 + ch) * 64 + t];
        NORM[bh * 64 + t] = sn;
    }
}

// ---------------------------------------------------------------------------
// K3: tiny attention among 64 slice tokens per (b,h). 1 wave per block.
// ---------------------------------------------------------------------------
__global__ __launch_bounds__(64) void k3_attn(
    const float* __restrict__ ST, const float* __restrict__ NORM,
    const float* __restrict__ Wqkv, float* __restrict__ OST)
{
    __shared__ float Wq[32 * 96];
    __shared__ float Kl[64][32];
    __shared__ float Vl[64][32];
    __shared__ float Dl[64][68];
    const int bh = blockIdx.x;
    const int s  = threadIdx.x;

    for (int i = 0; i < 48; ++i) Wq[i * 64 + s] = Wqkv[i * 64 + s];
    float st[32];
    const float nrm = NORM[bh * 64 + s] + 1e-5f;
#pragma unroll
    for (int c = 0; c < 32; ++c) st[c] = ST[bh * 2048 + s * 32 + c] / nrm;
    __syncthreads();

    float q[32];
#pragma unroll
    for (int o4 = 0; o4 < 8; ++o4) {
        float ax = 0.f, ay = 0.f, az = 0.f, aw = 0.f;
#pragma unroll
        for (int c = 0; c < 32; ++c) {
            float4 w = *(const float4*)&Wq[c * 96 + o4 * 4];
            ax = fmaf(st[c], w.x, ax); ay = fmaf(st[c], w.y, ay);
            az = fmaf(st[c], w.z, az); aw = fmaf(st[c], w.w, aw);
        }
        q[o4 * 4 + 0] = ax; q[o4 * 4 + 1] = ay; q[o4 * 4 + 2] = az; q[o4 * 4 + 3] = aw;
    }
#pragma unroll
    for (int o4 = 0; o4 < 8; ++o4) {
        float ax = 0.f, ay = 0.f, az = 0.f, aw = 0.f;
#pragma unroll
        for (int c = 0; c < 32; ++c) {
            float4 w = *(const float4*)&Wq[c * 96 + 32 + o4 * 4];
            ax = fmaf(st[c], w.x, ax); ay = fmaf(st[c], w.y, ay);
            az = fmaf(st[c], w.z, az); aw = fmaf(st[c], w.w, aw);
        }
        float4 kv; kv.x = ax; kv.y = ay; kv.z = az; kv.w = aw;
        *(float4*)&Kl[s][o4 * 4] = kv;
    }
#pragma unroll
    for (int o4 = 0; o4 < 8; ++o4) {
        float ax = 0.f, ay = 0.f, az = 0.f, aw = 0.f;
#pragma unroll
        for (int c = 0; c < 32; ++c) {
            float4 w = *(const float4*)&Wq[c * 96 + 64 + o4 * 4];
            ax = fmaf(st[c], w.x, ax); ay = fmaf(st[c], w.y, ay);
            az = fmaf(st[c], w.z, az); aw = fmaf(st[c], w.w, aw);
        }
        float4 vv; vv.x = ax; vv.y = ay; vv.z = az; vv.w = aw;
        *(float4*)&Vl[s][o4 * 4] = vv;
    }
    __syncthreads();

    const float scale = 0.17677669529663687f;  // 32^-0.5
    float mx = -1e30f;
    for (int t2 = 0; t2 < 64; ++t2) {
        float d = 0.f;
#pragma unroll
        for (int c4 = 0; c4 < 8; ++c4) {
            float4 kv = *(const float4*)&Kl[t2][c4 * 4];
            d = fmaf(q[c4 * 4 + 0], kv.x, d); d = fmaf(q[c4 * 4 + 1], kv.y, d);
            d = fmaf(q[c4 * 4 + 2], kv.z, d); d = fmaf(q[c4 * 4 + 3], kv.w, d);
        }
        d *= scale;
        Dl[s][t2] = d;
        mx = fmaxf(mx, d);
    }
    float sum = 0.f;
    for (int t2 = 0; t2 < 64; ++t2) { float e = expf(Dl[s][t2] - mx); Dl[s][t2] = e; sum += e; }
    const float inv = 1.0f / sum;
    float out[32];
#pragma unroll
    for (int c = 0; c < 32; ++c) out[c] = 0.f;
    for (int t2 = 0; t2 < 64; ++t2) {
        const float p = Dl[s][t2] * inv;
#pragma unroll
        for (int c4 = 0; c4 < 8; ++c4) {
            float4 vv = *(const float4*)&Vl[t2][c4 * 4];
            out[c4 * 4 + 0] = fmaf(p, vv.x, out[c4 * 4 + 0]);
            out[c4 * 4 + 1] = fmaf(p, vv.y, out[c4 * 4 + 1]);
            out[c4 * 4 + 2] = fmaf(p, vv.z, out[c4 * 4 + 2]);
            out[c4 * 4 + 3] = fmaf(p, vv.w, out[c4 * 4 + 3]);
        }
    }
#pragma unroll
    for (int c4 = 0; c4 < 8; ++c4) {
        float4 ov;
        ov.x = out[c4 * 4 + 0]; ov.y = out[c4 * 4 + 1];
        ov.z = out[c4 * 4 + 2]; ov.w = out[c4 * 4 + 3];
        *(float4*)&OST[bh * 2048 + s * 32 + c4 * 4] = ov;
    }
}

// ---------------------------------------------------------------------------
// K3b: G[b, h*64+s, :] = OST[bh,s,:] @ Wout[h*32:(h+1)*32, :], written
// TRANSPOSED as bf16 hi/lo: Gt[b][n=256][k=512].
// ---------------------------------------------------------------------------
__global__ __launch_bounds__(256) void k3b_precomb(
    const float* __restrict__ OST, const float* __restrict__ Wout,
    unsigned short* __restrict__ Gth, unsigned short* __restrict__ Gtl)
{
    __shared__ float OSTs[64][36];   // [s][c], padded
    __shared__ float Wc[32][256];    // [c][o]
    const int bh = blockIdx.x;
    const int b = bh >> 3, h = bh & 7;
    const int t = threadIdx.x;

#pragma unroll
    for (int j = 0; j < 2; ++j) {
        const int e = (j * 256 + t) * 4;       // 0..2044, step 4
        float4 v = *(const float4*)&OST[bh * 2048 + e];
        const int s = e >> 5, c = e & 31;
        OSTs[s][c + 0] = v.x; OSTs[s][c + 1] = v.y;
        OSTs[s][c + 2] = v.z; OSTs[s][c + 3] = v.w;
    }
#pragma unroll
    for (int j = 0; j < 8; ++j) {
        const int e = (j * 256 + t) * 4;       // 0..8188
        const int c = e >> 8, o = e & 255;
        *(float4*)&Wc[c][o] = *(const float4*)&Wout[(h * 32 + c) * 256 + o];
    }
    __syncthreads();

    float wcol[32];
#pragma unroll
    for (int c = 0; c < 32; ++c) wcol[c] = Wc[c][t];

    for (int s = 0; s < 64; ++s) {
        float a = 0.f;
#pragma unroll
        for (int c = 0; c < 32; ++c) a = fmaf(OSTs[s][c], wcol[c], a);
        const unsigned short gh = f2bf(a);
        const size_t idx = ((size_t)(b * 256 + t)) * 512 + h * 64 + s;
        Gth[idx] = gh;
        Gtl[idx] = f2bf(a - bf2f(gh));
    }
}

// ---------------------------------------------------------------------------
// K4: out = SW[131072x512] @ Gt_b^T + bout. 2048 blocks, XCD-swizzled pairs.
// A-path: reads SW f32, inline hi/lo split (k1's proven pattern).
// B-path: Gt hi/lo via global_load_lds. Single-buffer 2-barrier loop, K=512.
// ---------------------------------------------------------------------------
__global__ __launch_bounds__(256) void k4_gemm(
    const float* __restrict__ SW,
    const unsigned short* __restrict__ Gth, const unsigned short* __restrict__ Gtl,
    const float* __restrict__ bout, float* __restrict__ out)
{
    __shared__ unsigned short AldsH[4096];
    __shared__ unsigned short AldsL[4096];
    __shared__ unsigned short BldsH[4096];
    __shared__ unsigned short BldsL[4096];
    const int L = blockIdx.x;
    const int xcd = L & 7, ii = L >> 3;
    const int rb = xcd * 128 + (ii >> 1), nsel = ii & 1;
    const int row0 = rb * 128;
    const int n0 = nsel * 128;
    const int b = row0 >> 15;
    const unsigned short* Bth = Gth + ((size_t)b * 256 + n0) * 512;
    const unsigned short* Btl = Gtl + ((size_t)b * 256 + n0) * 512;

    const int t = threadIdx.x;
    const int w = t >> 6, l = t & 63;
    const int wm = w >> 1, wn = w & 1;
    const int lr = l & 15, lk = l >> 4;

    f32x4 acc[4][4];
#pragma unroll
    for (int i = 0; i < 4; ++i)
#pragma unroll
        for (int j = 0; j < 4; ++j) {
            acc[i][j][0] = 0.f; acc[i][j][1] = 0.f;
            acc[i][j][2] = 0.f; acc[i][j][3] = 0.f;
        }

    for (int step = 0; step < 16; ++step) {
        const int kk = step * 32;
        if (step > 0) __syncthreads();
        // B: async gload_lds (bf16 hi/lo pre-split; L2-resident, G is 512 KB)
#pragma unroll
        for (int g2i = 0; g2i < 2; ++g2i) {
            const int g2 = w + g2i * 4;
            const size_t br = (size_t)(g2 * 16 + lr) * 512 + kk + lk * 8;
            const int lb = g2 * 512;
            GL16(Bth + br, BldsH + lb);
            GL16(Btl + br, BldsL + lb);
        }
        // A: load SW f32, split hi/lo, ds_write (lane-linear, conflict-free)
#pragma unroll
        for (int g2i = 0; g2i < 2; ++g2i) {
            const int g2 = w + g2i * 4;
            const float* ap = &SW[(size_t)(row0 + g2 * 16 + lr) * 512 + kk + lk * 8];
            float4 a0 = *(const float4*)ap;
            float4 a1 = *(const float4*)(ap + 4);
            float cc[8] = {a0.x, a0.y, a0.z, a0.w, a1.x, a1.y, a1.z, a1.w};
            us8 vh, vl;
#pragma unroll
            for (int j = 0; j < 8; ++j) {
                const unsigned short hb = f2bf(cc[j]);
                vh[j] = hb;
                vl[j] = f2bf(cc[j] - bf2f(hb));
            }
            *(us8*)&AldsH[(g2 * 64 + l) * 8] = vh;
            *(us8*)&AldsL[(g2 * 64 + l) * 8] = vl;
        }
        __syncthreads();

        bf16x8 ah[4], al[4], bh[4], bl[4];
#pragma unroll
        for (int g = 0; g < 4; ++g) {
            const int ac = (((wm * 4 + g) * 4 + lk) * 16 + lr) * 8;
            ah[g] = *(const bf16x8*)&AldsH[ac];
            al[g] = *(const bf16x8*)&AldsL[ac];
            const int bc = (((wn * 4 + g) * 4 + lk) * 16 + lr) * 8;
            bh[g] = *(const bf16x8*)&BldsH[bc];
            bl[g] = *(const bf16x8*)&BldsL[bc];
        }
#pragma unroll
        for (int m = 0; m < 4; ++m)
#pragma unroll
            for (int n = 0; n < 4; ++n) {
                acc[m][n] = __builtin_amdgcn_mfma_f32_16x16x32_bf16(ah[m], bh[n], acc[m][n], 0, 0, 0);
                acc[m][n] = __builtin_amdgcn_mfma_f32_16x16x32_bf16(ah[m], bl[n], acc[m][n], 0, 0, 0);
                acc[m][n] = __builtin_amdgcn_mfma_f32_16x16x32_bf16(al[m], bh[n], acc[m][n], 0, 0, 0);
            }
    }

    float bv[4];
#pragma unroll
    for (int n = 0; n < 4; ++n) bv[n] = bout[n0 + wn * 64 + n * 16 + lr];
#pragma unroll
    for (int m = 0; m < 4; ++m)
#pragma unroll
        for (int n = 0; n < 4; ++n) {
            const int col = n0 + wn * 64 + n * 16 + lr;
#pragma unroll
            for (int r = 0; r < 4; ++r) {
                const int row = row0 + wm * 64 + m * 16 + lk * 4 + r;
                out[(size_t)row * 256 + col] = acc[m][n][r] + bv[n];
            }
        }
}

extern "C" void kernel_launch(void* const* d_in, const int* in_sizes, int n_in,
                              void* d_out, int out_size, void* d_ws, size_t ws_size,
                              hipStream_t stream) {
    (void)in_sizes; (void)n_in; (void)out_size; (void)ws_size;
    const float* x    = (const float*)d_in[0];
    const float* Wfx  = (const float*)d_in[1];
    const float* bfx  = (const float*)d_in[2];
    const float* Wx   = (const float*)d_in[3];
    const float* bx   = (const float*)d_in[4];
    const float* Wsl  = (const float*)d_in[5];
    const float* bsl  = (const float*)d_in[6];
    const float* temp = (const float*)d_in[7];
    const float* Wqkv = (const float*)d_in[8];
    const float* Wout = (const float*)d_in[9];
    const float* bout = (const float*)d_in[10];
    float* out = (float*)d_out;
    char* w = (char*)d_ws;

    // ws layout (bytes):
    // [0, 128M):       XM f32 (dead after k1b) -> reused for PART/PARTN by k2
    // [128M, 384M):    SW f32 [M][512]
    // [384M+, ...):    ST/NORM/OST/Gt/Wt
    float* XM = (float*)w;
    float* SW = (float*)(w + 134217728);          // 67,108,864 floats
    char* p = w + 134217728 + 268435456;
    float* ST    = (float*)p;            p += 262144;      // 65,536 f
    float* NORM  = (float*)p;            p += 8192;        // 2,048 f
    float* OST   = (float*)p;            p += 262144;      // 65,536 f
    unsigned short* Gth = (unsigned short*)p; p += 1048576; // 524,288 us
    unsigned short* Gtl = (unsigned short*)p; p += 1048576;
    unsigned short* Wth = (unsigned short*)p; p += 262144;  // 131,072 us
    unsigned short* Wtl = (unsigned short*)p; p += 262144;
    // PART/PARTN in the dead XM region
    float* PART  = XM;                   // 32*64*2048 = 4,194,304 f
    float* PARTN = XM + 4194304;         // 32*64*64  = 131,072 f
    float* FX = out;   // d_out doubles as FX scratch (read by k2, overwritten by k4)

    k0_wt<<<dim3(256, 2), 256, 0, stream>>>(Wfx, Wx, Wth, Wtl);
    k1_gemm<<<4096, 256, 0, stream>>>(x, Wth, Wtl, bfx, bx, FX, XM);
    k1b_slice_softmax<<<dim3(TS_M / 64, 8), 256, 0, stream>>>(XM, Wsl, bsl, temp, SW);
    k2_pool<<<dim3(64, 32), 256, 0, stream>>>(FX, SW, PART, PARTN);
    k2b_reduce<<<dim3(8, 32), 256, 0, stream>>>(PART, PARTN, ST, NORM);
    k3_attn<<<32, 64, 0, stream>>>(ST, NORM, Wqkv, OST);
    k3b_precomb<<<32, 256, 0, stream>>>(OST, Wout, Gth, Gtl);
    k4_gemm<<<2048, 256, 0, stream>>>(SW, Gth, Gtl, bout, out);
}